// Round 13
// baseline (1854.903 us; speedup 1.0000x reference)
//
#include <hip/hip_runtime.h>

#define NPIX 16384   // 16*32*32
#define DIM  256
#define NEMB 8192

// async 16B global->LDS (m97 pattern): LDS dest = wave-uniform base + lane*16
#define GLOAD16(g, l)                                                     \
  __builtin_amdgcn_global_load_lds(                                       \
      (const __attribute__((address_space(1))) void*)(g),                 \
      (__attribute__((address_space(3))) void*)(l), 16, 0, 0)

// ---------------- K0: codebook squared norms (one wave per code) ----------------
__global__ __launch_bounds__(256) void k_cbnorm(const float* __restrict__ cb,
                                                float* __restrict__ cbn) {
  const int wid  = blockIdx.x * 4 + (threadIdx.x >> 6);   // code index 0..8191
  const int lane = threadIdx.x & 63;
  const float4 v = reinterpret_cast<const float4*>(cb)[wid * 64 + lane];
  float s = v.x * v.x + v.y * v.y + v.z * v.z + v.w * v.w;
#pragma unroll
  for (int m = 32; m >= 1; m >>= 1) s += __shfl_xor(s, m, 64);
  if (lane == 0) cbn[wid] = s;
}

// ---------------- K1: transpose x [b][c][hw] -> xt [pix][c] ----------------
__global__ __launch_bounds__(256) void k_xpose(const float* __restrict__ x,
                                               float* __restrict__ xt) {
  __shared__ float tile[64][36];
  const int t = threadIdx.x, blk = blockIdx.x;
  const int b = blk >> 4, hw0 = (blk & 15) << 6;
  const size_t xbase = ((size_t)b << 18) + hw0;
  const int hwL = t & 63, cr = t >> 6;     // read mapping
  const int pixL = t >> 2, c4 = t & 3;     // write mapping
  for (int ch = 0; ch < 8; ++ch) {
    __syncthreads();
#pragma unroll
    for (int i = 0; i < 8; ++i) {
      const int cloc = cr + 4 * i;         // 0..31
      tile[hwL][cloc] = x[xbase + ((size_t)(ch * 32 + cloc) << 10) + hwL];
    }
    __syncthreads();
    const size_t row = (size_t)(b * 1024 + hw0 + pixL) * 256 + ch * 32 + c4 * 8;
#pragma unroll
    for (int u = 0; u < 2; ++u)
      *reinterpret_cast<float4*>(&xt[row + u * 4]) =
          *reinterpret_cast<const float4*>(&tile[pixL][c4 * 8 + u * 4]);
  }
}

// ---------------- K1b: x row squared norms + key init ------
__global__ __launch_bounds__(256) void k_xnorm(const float* __restrict__ xt,
                                               float* __restrict__ xn,
                                               unsigned long long* __restrict__ keys) {
  const int wid  = blockIdx.x * 4 + (threadIdx.x >> 6);   // pixel 0..16383
  const int lane = threadIdx.x & 63;
  const float4 v = reinterpret_cast<const float4*>(xt)[(size_t)wid * 64 + lane];
  float s = fmaf(v.x, v.x, fmaf(v.y, v.y, fmaf(v.z, v.z, v.w * v.w)));
#pragma unroll
  for (int m = 32; m >= 1; m >>= 1) s += __shfl_xor(s, m, 64);
  if (lane == 0) xn[wid] = s;
  if (lane == 1) keys[wid] = ~0ull;   // init for atomicMin
}

// ---------------- K2: argmin over codes (fp32 VALU GEMM) ----------------
// 512 blocks x 512 threads (2 blocks/CU). Block = (pixGroup = bid>>1)*64 pixels
// x code half (bid&1)*4096. 8 waves; wave w owns pixels {w+8i, i=0..7}; lane =
// code lane; codes k = half*4096 + ct*256 + lane + 64j (j=0..3).
// Stage = 256 codes x 32 c (csm 64 KB double-buffered), 128 stages.
// ca reused over 8 pixels -> 0.5 B LDS per FMA (FMA-bound, was 1.0 = LDS-bound).
// Staging via global_load_lds 16B, linear conflict-free map (4 slots/thread).
// Cross-half merge: packed u64 key atomicMin (monotone-float(d)<<32 | k) ==
// lexicographic (d,k) min == np first-index argmin.
// Numerics bit-identical to round-9/10 PASS: sequential ascending-c fmaf chain,
// d = R(R(cbn+xn) - 2*dot), per-thread ascending-k strict-<, lex (d,k) reduce.
__global__ __launch_bounds__(512, 4) void k_argmin(const float* __restrict__ xt,
                                                   const float* __restrict__ cb,
                                                   const float* __restrict__ cbn,
                                                   const float* __restrict__ xn,
                                                   unsigned long long* __restrict__ keys) {
  __shared__ float csm[2][8][256][4];   // [buf][q][code row][4 c] = 64 KB
  const int t    = threadIdx.x;
  const int lane = t & 63;
  const int w    = __builtin_amdgcn_readfirstlane(t >> 6);  // wave id 0..7
  const int bid  = blockIdx.x;
  const int half = bid & 1;
  const int p0   = (bid >> 1) * 64;
  const int kb   = half * 4096;
  const float* __restrict__ xw  = xt + (size_t)(p0 + w) * 256;  // uniform base
  const float* __restrict__ cbh = cb + (size_t)kb * 256;

  float xnr[8];
#pragma unroll
  for (int i = 0; i < 8; ++i) xnr[i] = xn[p0 + w + 8 * i];

  float bd[8];
  int   bk[8];
#pragma unroll
  for (int i = 0; i < 8; ++i) { bd[i] = 3.4e38f; bk[i] = 0; }

  float acc[8][4];

  // staging: thread t owns slots s in {t, t+512, t+1024, t+1536}; q=s>>8,
  // code=s&255; LDS float offset = s*4 (linear, wave-uniform base + lane*16).
  float* const lds0 = &csm[0][0][0][0];
  float* const lds1 = &csm[1][0][0][0];

  // prologue: stage 0 (ct=0, cc=0) -> buf0
#pragma unroll
  for (int r = 0; r < 4; ++r) {
    const int s = t + r * 512;
    GLOAD16(&cbh[(size_t)(s & 255) * 256 + (s >> 8) * 4], lds0 + (size_t)s * 4);
  }
  __syncthreads();

#pragma unroll 1
  for (int u = 0; u < 128; ++u) {
    const int buf = u & 1, ct = u >> 3, cc = u & 7;
    // issue async loads for stage u+1 into the other buffer
    if (u + 1 < 128) {
      const int u2 = u + 1, ct2 = u2 >> 3, cc2 = u2 & 7;
      float* const dst = (u & 1) ? lds0 : lds1;
#pragma unroll
      for (int r = 0; r < 4; ++r) {
        const int s = t + r * 512;
        GLOAD16(&cbh[(size_t)(ct2 * 256 + (s & 255)) * 256 + cc2 * 32 + (s >> 8) * 4],
                dst + (size_t)s * 4);
      }
    }
    if (cc == 0) {
#pragma unroll
      for (int i = 0; i < 8; ++i)
#pragma unroll
        for (int j = 0; j < 4; ++j) acc[i][j] = 0.f;
    }
#pragma unroll
    for (int q = 0; q < 8; ++q) {
      float4 xa[8], ca[4];
#pragma unroll
      for (int i = 0; i < 8; ++i)
        xa[i] = *reinterpret_cast<const float4*>(&xw[i * 2048 + cc * 32 + q * 4]);
#pragma unroll
      for (int j = 0; j < 4; ++j)
        ca[j] = *reinterpret_cast<const float4*>(&csm[buf][q][lane + 64 * j][0]);
#pragma unroll
      for (int i = 0; i < 8; ++i)
#pragma unroll
        for (int j = 0; j < 4; ++j) {
          acc[i][j] = fmaf(xa[i].x, ca[j].x, acc[i][j]);
          acc[i][j] = fmaf(xa[i].y, ca[j].y, acc[i][j]);
          acc[i][j] = fmaf(xa[i].z, ca[j].z, acc[i][j]);
          acc[i][j] = fmaf(xa[i].w, ca[j].w, acc[i][j]);
        }
    }
    if (cc == 7) {   // epilogue for code tile ct
#pragma unroll
      for (int j = 0; j < 4; ++j) {
        const int k = kb + ct * 256 + lane + 64 * j;
        const float cn = cbn[k];
#pragma unroll
        for (int i = 0; i < 8; ++i) {
          const float sq2 = cn + xnr[i];
          const float d   = fmaf(-2.f, acc[i][j], sq2);
          if (d < bd[i]) { bd[i] = d; bk[i] = k; }   // ascending k -> first-min kept
        }
      }
    }
    __syncthreads();
  }

  // per-pixel lexicographic (d, k) min across the 64 lanes, then global atomic
#pragma unroll
  for (int i = 0; i < 8; ++i) {
    float d = bd[i];
    int   k = bk[i];
#pragma unroll
    for (int off = 32; off >= 1; off >>= 1) {
      const float d2 = __shfl_xor(d, off, 64);
      const int   k2 = __shfl_xor(k, off, 64);
      if (d2 < d || (d2 == d && k2 < k)) { d = d2; k = k2; }
    }
    if (lane == 0) {
      unsigned ub = __float_as_uint(d);
      ub ^= (unsigned)(((int)ub >> 31) | 0x80000000);   // monotone float->uint
      const unsigned long long key = ((unsigned long long)ub << 32) | (unsigned)k;
      atomicMin(&keys[p0 + w + 8 * i], key);
    }
  }
}

// ---------------- K3: gather + emb_out + ids-as-float + loss partials ----------------
__global__ __launch_bounds__(256) void k_out(const float* __restrict__ x,
                                             const float* __restrict__ cb,
                                             const unsigned long long* __restrict__ keys,
                                             float* __restrict__ out,
                                             double* __restrict__ partials) {
  __shared__ float  es[64 * 68];
  __shared__ double red[256];
  const int t = threadIdx.x, blk = blockIdx.x;
  const int n0 = blk * 64;
  const int b = blk >> 4, hw0 = (blk & 15) << 6;
  const size_t xbase = ((size_t)b << 18) + hw0;
  const int p = t >> 2, c4 = t & 3;        // staging
  const int lane = t & 63, cgr = t >> 6;   // compute
  double acc = 0.0;
  float* out_emb = out + NPIX;
  for (int cc = 0; cc < 4; ++cc) {
    const int cbase = cc * 64;
    __syncthreads();
    const int id = (int)(unsigned)keys[n0 + p];
#pragma unroll
    for (int i = 0; i < 4; ++i) {
      const int cl = c4 * 16 + i * 4;
      *reinterpret_cast<float4*>(&es[p * 68 + cl]) =
          *reinterpret_cast<const float4*>(&cb[(size_t)id * 256 + cbase + cl]);
    }
    __syncthreads();
#pragma unroll
    for (int i = 0; i < 16; ++i) {
      const int c = cgr * 16 + i;
      const size_t g = xbase + ((size_t)(cbase + c) << 10) + lane;
      const float xv = x[g];
      const float ev = es[lane * 68 + c];
      const float d = xv - ev;
      acc += (double)d * (double)d;
      out_emb[g] = xv + (ev - xv);   // replicate straight-through rounding exactly
    }
  }
  if (t < 64) out[n0 + t] = (float)(int)(unsigned)keys[n0 + t];
  __syncthreads();
  red[t] = acc;
  __syncthreads();
  for (int sft = 128; sft >= 1; sft >>= 1) {
    if (t < sft) red[t] += red[t + sft];
    __syncthreads();
  }
  if (t == 0) partials[blk] = red[0];
}

// ---------------- K4: finalize loss ----------------
__global__ __launch_bounds__(256) void k_loss(const double* __restrict__ partials,
                                              float* __restrict__ out) {
  __shared__ double red[256];
  const int t = threadIdx.x;
  red[t] = partials[t];
  __syncthreads();
  for (int sft = 128; sft >= 1; sft >>= 1) {
    if (t < sft) red[t] += red[t + sft];
    __syncthreads();
  }
  if (t == 0) {
    const float m = (float)(red[0] / 4194304.0);     // mean((x-emb)^2)
    out[NPIX + (size_t)NPIX * 256] = m + 0.25f * m;  // dict + BETA*commitment
  }
}

extern "C" void kernel_launch(void* const* d_in, const int* in_sizes, int n_in,
                              void* d_out, int out_size, void* d_ws, size_t ws_size,
                              hipStream_t stream) {
  const float* x  = (const float*)d_in[0];   // [16,256,32,32]
  const float* cb = (const float*)d_in[1];   // [8192,256]
  float* out = (float*)d_out;                // [ids | emb_out | loss]

  char* wsb = (char*)d_ws;
  float*  cbn = (float*)wsb;                                        // 32 KB
  float*  xn  = (float*)(wsb + (32 << 10));                         // 64 KB
  unsigned long long* keys = (unsigned long long*)(wsb + (96 << 10)); // 128 KB
  double* partials = (double*)(wsb + (224 << 10));                  // 2 KB
  // xt: 16 MB. Use ws if it fits, else borrow the emb_out region of d_out
  // (k_xpose writes it, k_argmin reads it, k_out overwrites it afterwards).
  const size_t need = (256 << 10) + (size_t)NPIX * DIM * 4;
  float* xt = (ws_size >= need) ? (float*)(wsb + (256 << 10)) : (out + NPIX);

  k_xpose <<<256,  256, 0, stream>>>(x, xt);
  k_cbnorm<<<2048, 256, 0, stream>>>(cb, cbn);
  k_xnorm <<<4096, 256, 0, stream>>>(xt, xn, keys);
  k_argmin<<<512,  512, 0, stream>>>(xt, cb, cbn, xn, keys);
  k_out   <<<256,  256, 0, stream>>>(x, cb, keys, out, partials);
  k_loss  <<<1,    256, 0, stream>>>(partials, out);
}